// Round 4
// baseline (60.707 us; speedup 1.0000x reference)
//
#include <hip/hip_runtime.h>
#include <stdint.h>

#define N_SAMP 8192
#define D_DIM  512
#define P_DIM  1024
#define DT     0.1875f

typedef float f32x4 __attribute__((ext_vector_type(4)));
typedef float f32x2 __attribute__((ext_vector_type(2)));
typedef short bf16x8 __attribute__((ext_vector_type(8)));
typedef unsigned short u16;

__device__ __forceinline__ u16 f2bf(float x){
    unsigned int u = __float_as_uint(x);
    return (u16)((u + 0x7FFFu + ((u >> 16) & 1u)) >> 16);
}

__device__ __forceinline__ void load_lds16(const void* g, void* l){
    __builtin_amdgcn_global_load_lds(
        (const __attribute__((address_space(1))) void*)(uintptr_t)g,
        (__attribute__((address_space(3))) void*)(uint32_t)(uintptr_t)l,
        16, 0, 0);
}

// ---- prep: blocks 0..4095 convert z->bf16; blocks 4096..4127 each own a
//      32-column strip of A: compute norms + write transposed bf16 AnT ----
__global__ __launch_bounds__(256) void k_prep(const float4* __restrict__ z4,
                                              u16* __restrict__ zb,
                                              const float* __restrict__ A,
                                              u16* __restrict__ AnT,
                                              float* __restrict__ out){
    const int tid = threadIdx.x;
    if (blockIdx.x < 4096){
        int i = blockIdx.x * 256 + tid;       // N*D/4 threads
        if (i == 0) out[0] = 0.f;             // stream-ordered before k_reduce
        float4 v = z4[i];
        ushort4 o;
        o.x = f2bf(v.x); o.y = f2bf(v.y); o.z = f2bf(v.z); o.w = f2bf(v.w);
        ((ushort4*)zb)[i] = o;
        return;
    }
    __shared__ float tile[32][33];
    __shared__ float red[8][32];
    __shared__ float inv_s[32];
    const int p0 = (blockIdx.x - 4096) * 32;
    const int pl = tid & 31, dg = tid >> 5;   // 32 p-lanes x 8 d-groups
    // phase 1: column square-sums (coalesced 128B per 32-lane group)
    float s = 0.f;
    #pragma unroll 8
    for (int i = 0; i < 64; ++i){
        float v = A[(size_t)(dg + 8 * i) * P_DIM + p0 + pl];
        s += v * v;
    }
    red[dg][pl] = s;
    __syncthreads();
    if (tid < 32){
        float t = 0.f;
        #pragma unroll
        for (int g = 0; g < 8; ++g) t += red[g][tid];
        inv_s[tid] = 1.0f / fmaxf(sqrtf(t), 1e-8f);
    }
    __syncthreads();
    // phase 2: 16 LDS tile transposes (A rows L2-hot from phase 1)
    for (int dt = 0; dt < 16; ++dt){
        #pragma unroll
        for (int ii = 0; ii < 4; ++ii)
            tile[dg + ii * 8][pl] =
                A[(size_t)(dt * 32 + dg + ii * 8) * P_DIM + p0 + pl];
        __syncthreads();
        #pragma unroll
        for (int ii = 0; ii < 4; ++ii){
            int pr = dg + ii * 8;
            AnT[(size_t)(p0 + pr) * D_DIM + dt * 32 + pl] =
                f2bf(tile[pl][pr] * inv_s[pr]);
        }
        __syncthreads();
    }
}

// ---- fused GEMM + ECF: A via XOR-swizzled LDS dbuf, B direct from L2 ----
__global__ __launch_bounds__(256) void k_gemm_ecf(const u16* __restrict__ zb,
                                                  const u16* __restrict__ AnT,
                                                  float* __restrict__ partial){
    __shared__ uint4 smem4[2048];                 // 32 KiB: 2 x 16 KiB A bufs
    const int tid = threadIdx.x;
    const int bm = blockIdx.x >> 3, bn = blockIdx.x & 7;
    const int m0 = bm << 7, n0 = bn << 7;
    const int w = tid >> 6, lane = tid & 63;
    const int r = lane & 15, kg = lane >> 4;
    const int wm = (w >> 1) << 6, wn = (w & 1) << 6;

    // A staging: thread t -> LDS granule (row=t>>3, g=t&7) linear; global
    // source granule (t&7)^(row&7) (inverse of the read swizzle).
    const int srow = tid >> 3;
    const int gsw  = ((tid & 7) ^ (srow & 7)) << 3;
    const u16* gA = zb + (size_t)(m0 + srow) * D_DIM + gsw;
    char* lbase = (char*)smem4 + w * 1024;        // wave-uniform base

    // B fragments: lane-fixed global row base (fully L2-resident, 1 MB)
    const u16* gB = AnT + (size_t)(n0 + wn + r) * D_DIM + kg * 8;

    f32x4 acc[4][4] = {};

    #pragma unroll
    for (int i = 0; i < 4; ++i)                   // prologue: A tile 0 -> buf0
        load_lds16(gA + (size_t)i * 32 * D_DIM, lbase + i * 4096);

    for (int kt = 0; kt < 8; ++kt){
        const int cur = kt & 1;
        __syncthreads();                          // cur A-buf ready, prev reads done
        if (kt < 7){                              // prefetch next A tile
            char* la = lbase + ((kt + 1) & 1) * 16384;
            #pragma unroll
            for (int i = 0; i < 4; ++i)
                load_lds16(gA + (size_t)i * 32 * D_DIM + (kt + 1) * 64,
                           la + i * 4096);
        }
        bf16x8 bfr[2][4];                         // issue all B loads up front
        #pragma unroll
        for (int ks = 0; ks < 2; ++ks)
            #pragma unroll
            for (int j = 0; j < 4; ++j)
                bfr[ks][j] = *(const bf16x8*)&gB[(size_t)j * 16 * D_DIM +
                                                 kt * 64 + ks * 32];
        const u16* Ab = (const u16*)smem4 + cur * 8192;
        #pragma unroll
        for (int ks = 0; ks < 2; ++ks){
            bf16x8 af[4];
            #pragma unroll
            for (int i = 0; i < 4; ++i)
                af[i] = *(const bf16x8*)&Ab[(wm + i * 16 + r) * 64 +
                                            (((ks * 4 + kg) ^ (r & 7)) << 3)];
            #pragma unroll
            for (int i = 0; i < 4; ++i)
                #pragma unroll
                for (int j = 0; j < 4; ++j)
                    acc[i][j] = __builtin_amdgcn_mfma_f32_16x16x32_bf16(
                        af[i], bfr[ks][j], acc[i][j], 0, 0, 0);
        }
    }

    // ---- epilogue: packed (cos,sin) Chebyshev recurrence, reduce rows ----
    __syncthreads();                              // done with A LDS bufs
    float* epil = (float*)smem4;                  // [4 waves][32 j][64 cols]
    #pragma unroll
    for (int jn = 0; jn < 4; ++jn){
        f32x2 sum[16];
        #pragma unroll
        for (int k = 0; k < 16; ++k) sum[k] = (f32x2){0.f, 0.f};
        #pragma unroll
        for (int i = 0; i < 4; ++i){
            #pragma unroll
            for (int q = 0; q < 4; ++q){
                float x = acc[i][jn][q] * DT;     // theta = proj * t1
                float c1 = __cosf(x), s1 = __sinf(x);
                float tc = c1 + c1;
                f32x2 prev = {1.f, 0.f};
                f32x2 curv = {c1, s1};
                sum[0] += curv;
                #pragma unroll
                for (int k = 2; k <= 16; ++k){
                    f32x2 nxt = tc * curv - prev; // v_pk_fma_f32
                    sum[k - 1] += nxt;
                    prev = curv; curv = nxt;
                }
            }
        }
        #pragma unroll
        for (int k = 0; k < 16; ++k){
            f32x2 o;
            o.x = __shfl_xor(sum[k].x, 16); o.y = __shfl_xor(sum[k].y, 16);
            sum[k] += o;
            o.x = __shfl_xor(sum[k].x, 32); o.y = __shfl_xor(sum[k].y, 32);
            sum[k] += o;
        }
        if (lane < 16){
            const int cl = jn * 16 + lane;
            #pragma unroll
            for (int k = 0; k < 16; ++k){
                epil[(w * 32 + k)      * 64 + cl] = sum[k].x;
                epil[(w * 32 + 16 + k) * 64 + cl] = sum[k].y;
            }
        }
    }
    __syncthreads();
    // fold row-halves (waves w, w+2), write partial[bm][j][p] coalesced
    for (int f0 = 0; f0 < 4096; f0 += 256){
        int f = f0 + tid;
        int cl = f & 127, j = f >> 7;
        int whi = cl >> 6, cll = cl & 63;
        float v = epil[(whi * 32 + j) * 64 + cll] +
                  epil[((whi + 2) * 32 + j) * 64 + cll];
        partial[((size_t)bm * 32 + j) * 1024 + n0 + cl] = v;
    }
}

// ---- reduce: 4 threads per (j,p) pair (16 slots each), weighted, atomic ----
__global__ __launch_bounds__(256) void k_reduce(const float* __restrict__ partial,
                                                float* __restrict__ out){
    const int tid = threadIdx.x;
    const int gt = blockIdx.x * 256 + tid;        // 0..131071
    const int pair = gt >> 2, quarter = gt & 3;
    const int p = pair & 1023, j = pair >> 10;    // j: 0..15 cos, 16..31 sin
    float s = 0.f;
    #pragma unroll
    for (int i = 0; i < 16; ++i)
        s += partial[((size_t)(quarter * 16 + i) * 32 + j) * 1024 + p];
    s += __shfl_xor(s, 1);
    s += __shfl_xor(s, 2);                        // full 64-slot sum, x4 copies
    const int k = (j & 15) + 1;
    float tk = (float)k * DT;
    float phik = expf(-0.5f * tk * tk);
    float wk = ((k == 16) ? DT : 2.f * DT) * phik;
    float mean = s * (1.f / (float)N_SAMP);
    float diff = (j < 16) ? (mean - phik) : mean;
    float term = diff * diff * wk;
    #pragma unroll
    for (int o = 32; o > 0; o >>= 1) term += __shfl_xor(term, o);
    __shared__ float red[4];
    if ((tid & 63) == 0) red[tid >> 6] = term;
    __syncthreads();
    if (tid == 0)
        atomicAdd(out, (red[0] + red[1] + red[2] + red[3]) * 0.25f *
                       ((float)N_SAMP / (float)P_DIM));
}

extern "C" void kernel_launch(void* const* d_in, const int* in_sizes, int n_in,
                              void* d_out, int out_size, void* d_ws, size_t ws_size,
                              hipStream_t stream){
    const float* z = (const float*)d_in[0];
    const float* A = (const float*)d_in[1];
    char* ws = (char*)d_ws;
    u16*   AnT     = (u16*)  (ws + 8192);         // 1 MiB  [1024][512] bf16
    u16*   zb      = (u16*)  (ws + 1056768);      // 8 MiB  [8192][512] bf16
    float* partial = (float*)(ws + 9445376);      // 8 MiB  [64][32][1024] f32
    float* out     = (float*)d_out;

    hipLaunchKernelGGL(k_prep,     dim3(4128), dim3(256), 0, stream,
                       (const float4*)z, zb, A, AnT, out);
    hipLaunchKernelGGL(k_gemm_ecf, dim3(512),  dim3(256), 0, stream, zb, AnT, partial);
    hipLaunchKernelGGL(k_reduce,   dim3(512),  dim3(256), 0, stream, partial, out);
}